// Round 11
// baseline (378.917 us; speedup 1.0000x reference)
//
#include <hip/hip_runtime.h>

#define LOOKBACK 48
#define HORIZON  12
#define TTOT     60
#define INPUT_DIM 8
#define HIDDEN   128
#define GATES    512
#define BATCH    8192
#define TILE_B   32          /* batch rows per block (2 M-tiles of 16) */
#define NTHREADS 512         /* 8 waves; wave s owns hidden units s*16..s*16+15 */
#define NSLICES  8
#define L0_KS    5           /* layer0 K = 160 (8 x + 128 h0 + 24 zero-pad) */
#define L1_KS    8           /* layer1 K = 256 (128 h0 + 128 h1) */
#define NPOS     (L0_KS + L1_KS)   /* 13 K-step positions per step */
#define NSTREAM  6           /* positions 0..5 streamed from L2 */
#define NPERS    7           /* positions 6..12 persistent in VGPRs (112 regs) */
#define FRAGS_PER_KS 4       /* 4 gate-type N-tiles, single fp16 B */
#define FRAG_SHORTS 512      /* 1KB per fragment */
#define KSTRIDE  (FRAGS_PER_KS * FRAG_SHORTS)            /* 2048 halves per K-step */
#define SLICE_FRAGS (NPOS * FRAGS_PER_KS)                /* 52 */
#define W_HALFS  (NSLICES * SLICE_FRAGS * FRAG_SHORTS)   /* 212992 halves = 416KB */

/* A-plane LDS, parity double-buffered (1 barrier/encoder step):
   A0[par]: chunk0 = x, chunks 1..16 = h0 (chunk 1+(u>>3)), 17..19 zero pad.
   A1[par]: chunks 0..15 = h1.
   chunk = [ROWP rows][8 fp16], ROWP=33 (32 rows + 1 pad row). */
#define ROWP 33
#define A0_CHUNKS 20
#define A1_CHUNKS 16
#define A0_BUF (A0_CHUNKS * ROWP * 8)      /* 5280 */
#define A1_BUF (A1_CHUNKS * ROWP * 8)      /* 4224 */
#define A0_HALFS (2 * A0_BUF)
#define A1_HALFS (2 * A1_BUF)

typedef __attribute__((ext_vector_type(8))) _Float16 half8;
typedef __attribute__((ext_vector_type(4))) float f32x4;

__device__ __forceinline__ float frcp(float x) { return __builtin_amdgcn_rcpf(x); }
__device__ __forceinline__ float sigm(float x) {
    return frcp(1.0f + __expf(-x));
}
/* tanh(x) = 2*sigm(2x)-1 : 5 VALU ops, exact at extremes (rcp(inf)=0) */
__device__ __forceinline__ float tanh_fast(float x) {
    return __builtin_fmaf(2.0f, frcp(1.0f + __expf(-2.0f * x)), -1.0f);
}

/* Barrier WITHOUT vmcnt drain: LDS ordering only; global loads stay in flight. */
#define BARRIER() __asm__ volatile("s_waitcnt lgkmcnt(0)\ns_barrier" ::: "memory")

// ------------- setup: fp16 weights in MFMA-fragment order -------------
__global__ void setup_kernel(const float* __restrict__ Wih0, const float* __restrict__ Whh0,
                             const float* __restrict__ bi0,  const float* __restrict__ bh0,
                             const float* __restrict__ Wih1, const float* __restrict__ Whh1,
                             const float* __restrict__ bi1,  const float* __restrict__ bh1,
                             _Float16* __restrict__ wfrag, float* __restrict__ bias) {
    int idx = blockIdx.x * blockDim.x + threadIdx.x;
    if (idx < W_HALFS) {
        int e = idx & 511, frag = idx >> 9;
        int lane = e >> 3, j = e & 7;
        int t = frag & 3;
        int rest = frag >> 2;
        int lks = rest % NPOS, s = rest / NPOS;
        int l = (lks < L0_KS) ? 0 : 1;
        int ks = l ? (lks - L0_KS) : lks;
        int k = ks * 32 + ((lane >> 4) << 3) + j;
        int uu = s * 16 + (lane & 15);
        int row = t * HIDDEN + uu;
        float v = 0.0f;
        if (l == 0) {
            if (k < INPUT_DIM) v = Wih0[row * INPUT_DIM + k];
            else if (k < INPUT_DIM + HIDDEN) v = Whh0[row * HIDDEN + (k - INPUT_DIM)];
        } else {
            if (k < HIDDEN) v = Wih1[row * HIDDEN + k];
            else v = Whh1[row * HIDDEN + (k - HIDDEN)];
        }
        wfrag[idx] = (_Float16)v;
    } else if (idx < W_HALFS + 2 * GATES) {
        int g = idx - W_HALFS;
        bias[g] = (g < GATES) ? (bi0[g] + bh0[g]) : (bi1[g - GATES] + bh1[g - GATES]);
    }
}

// ------------- persistent 2-layer LSTM: 7/13 K-steps of B live in VGPRs -------------
__global__ __launch_bounds__(NTHREADS, 2)
void lstm_kernel(const float* __restrict__ input,   // [B,60,8]
                 const _Float16* __restrict__ wfrag,
                 const float* __restrict__ bias01,  // [1024]
                 const float* __restrict__ W_fc,    // [128]
                 const float* __restrict__ b_fc,
                 float* __restrict__ out) {         // [B,12]
    __shared__ _Float16 A0[A0_HALFS];
    __shared__ _Float16 A1[A1_HALFS];
    __shared__ float wfcs[HIDDEN];

    const int tid  = threadIdx.x;
    const int lane = tid & 63;
    const int s    = tid >> 6;
    const int col  = lane & 15;
    const int quad = lane >> 4;
    const int u    = s * 16 + col;
    const int batch0 = blockIdx.x * TILE_B;

    /* wave-uniform weight base -> SGPR addressing */
    uintptr_t wp64 = (uintptr_t)(wfrag + s * (SLICE_FRAGS * FRAG_SHORTS));
    wp64 = ((uintptr_t)__builtin_amdgcn_readfirstlane((unsigned)(wp64 >> 32)) << 32)
         | __builtin_amdgcn_readfirstlane((unsigned)wp64);
    const _Float16* wbase = (const _Float16*)wp64;

    for (int i = tid; i < A0_HALFS; i += NTHREADS) A0[i] = (_Float16)0.f;
    for (int i = tid; i < A1_HALFS; i += NTHREADS) A1[i] = (_Float16)0.f;
    if (tid < HIDDEN) wfcs[tid] = W_fc[tid];
    const float bfc = b_fc[0];

    float bv0[4], bv1[4];
#pragma unroll
    for (int tt = 0; tt < 4; ++tt) {
        bv0[tt] = bias01[tt * HIDDEN + u];
        bv1[tt] = bias01[GATES + tt * HIDDEN + u];
    }

    float c0[2][4] = {}, c1[2][4] = {};

    // ---- persistent B: positions 6..12 -> 112 VGPRs, loaded once ----
    half8 bp[NPERS][4];
#pragma unroll
    for (int p = 0; p < NPERS; ++p)
#pragma unroll
        for (int tt = 0; tt < 4; ++tt)
            bp[p][tt] = *(const half8*)(wbase + (NSTREAM + p) * KSTRIDE
                                        + tt * FRAG_SHORTS + lane * 8);

    // x(0) prefetch + stage into parity-0 buffer
    float xv = 0.0f;
    if (tid < TILE_B * INPUT_DIM)
        xv = input[(size_t)(batch0 + (tid >> 3)) * (TTOT * INPUT_DIM) + (tid & 7)];
    BARRIER();                               // zero-init visible
    if (tid < TILE_B * INPUT_DIM)
        A0[(tid >> 3) * 8 + (tid & 7)] = (_Float16)xv;

    half8 bq[2][4];                          // streamed-B conveyor (depth 2)
    half8 ah[2][2];                          // A double buffer x 2 M-tiles

#define LOADB(p, sl) {                                                          \
    _Pragma("unroll") for (int tt = 0; tt < 4; ++tt)                            \
        bq[sl][tt] = *(const half8*)(wbase + (p) * KSTRIDE                      \
                                     + tt * FRAG_SHORTS + lane * 8); }
#define LOADA(H, off, chunk, buf) { int base_ = (off) + ((chunk) * ROWP + col) * 8; \
    ah[buf][0] = *(const half8*)(H + base_);                                    \
    ah[buf][1] = *(const half8*)(H + base_ + 16 * 8); }
#define COMPQ(ACC, ab, sl)                                                      \
    _Pragma("unroll") for (int tt = 0; tt < 4; ++tt)                            \
    _Pragma("unroll") for (int mt = 0; mt < 2; ++mt)                            \
        ACC[mt][tt] = __builtin_amdgcn_mfma_f32_16x16x32_f16(                   \
            ah[ab][mt], bq[sl][tt], ACC[mt][tt], 0, 0, 0);
#define COMPP(ACC, ab, i)                                                       \
    _Pragma("unroll") for (int tt = 0; tt < 4; ++tt)                            \
    _Pragma("unroll") for (int mt = 0; mt < 2; ++mt)                            \
        ACC[mt][tt] = __builtin_amdgcn_mfma_f32_16x16x32_f16(                   \
            ah[ab][mt], bp[i][tt], ACC[mt][tt], 0, 0, 0);

    LOADB(0, 0) LOADB(1, 1)                  // prime conveyor
    BARRIER();                               // x(0) staged & visible

#pragma unroll 1
    for (int t = 0; t < TTOT; ++t) {
        const int rb = t & 1, wb = rb ^ 1;
        const int a0r = rb * A0_BUF, a0w = wb * A0_BUF;
        const int a1r = rb * A1_BUF, a1w = wb * A1_BUF;

        // prefetch x(t+1)
        if (tid < TILE_B * INPUT_DIM && t + 1 < TTOT)
            xv = input[(size_t)(batch0 + (tid >> 3)) * (TTOT * INPUT_DIM)
                       + (t + 1) * INPUT_DIM + (tid & 7)];

        // ======== P1: GEMM0 reads A0[rb]; streamed pos 0..4 ========
        f32x4 acc[2][4];
#pragma unroll
        for (int tt = 0; tt < 4; ++tt) {
            f32x4 b = {bv0[tt], bv0[tt], bv0[tt], bv0[tt]};
            acc[0][tt] = b; acc[1][tt] = b;
        }
        LOADA(A0, a0r, quad, 0)
        LOADA(A0, a0r, 4 + quad, 1)  COMPQ(acc, 0, 0) LOADB(2, 0)   // pos0
        LOADA(A0, a0r, 8 + quad, 0)  COMPQ(acc, 1, 1) LOADB(3, 1)   // pos1
        LOADA(A0, a0r, 12 + quad, 1) COMPQ(acc, 0, 0) LOADB(4, 0)   // pos2
        LOADA(A0, a0r, 16 + quad, 0) COMPQ(acc, 1, 1) LOADB(5, 1)   // pos3
                                     COMPQ(acc, 0, 0) LOADB(0, 0)   // pos4; next-t pos0

        // cell 0 -> h0(t) into A0[wb] chunks 1..16
#pragma unroll
        for (int mt = 0; mt < 2; ++mt) {
#pragma unroll
            for (int r = 0; r < 4; ++r) {
                float ig = sigm(acc[mt][0][r]);
                float fg = sigm(acc[mt][1][r]);
                float gg = tanh_fast(acc[mt][2][r]);
                float og = sigm(acc[mt][3][r]);
                float cn = fg * c0[mt][r] + ig * gg;
                c0[mt][r] = cn;
                float h = og * tanh_fast(cn);
                int row = mt * 16 + quad * 4 + r;
                A0[a0w + ((1 + (u >> 3)) * ROWP + row) * 8 + (u & 7)] = (_Float16)h;
            }
        }
        // stage x(t+1) into A0[wb] chunk 0 (BG slot filled by fc for decode)
        if (tid < TILE_B * INPUT_DIM && t + 1 < TTOT) {
            int r = tid >> 3, k = tid & 7;
            if (!(t + 1 > LOOKBACK && k == 0))
                A0[a0w + r * 8 + k] = (_Float16)xv;
        }
        BARRIER();                           // the ONLY encoder barrier

        // ======== P2: GEMM1 reads h0 from A0[wb], h1 from A1[rb]; pos 5..12 ========
#pragma unroll
        for (int tt = 0; tt < 4; ++tt) {
            f32x4 b = {bv1[tt], bv1[tt], bv1[tt], bv1[tt]};
            acc[0][tt] = b; acc[1][tt] = b;
        }
        LOADA(A0, a0w, 1 + quad, 0)
        LOADA(A0, a0w, 5 + quad, 1)   COMPQ(acc, 0, 1) LOADB(1, 1)  // pos5; next-t pos1
        LOADA(A0, a0w, 9 + quad, 0)   COMPP(acc, 1, 0)              // pos6
        LOADA(A0, a0w, 13 + quad, 1)  COMPP(acc, 0, 1)              // pos7
        LOADA(A1, a1r, quad, 0)       COMPP(acc, 1, 2)              // pos8
        LOADA(A1, a1r, 4 + quad, 1)   COMPP(acc, 0, 3)              // pos9
        LOADA(A1, a1r, 8 + quad, 0)   COMPP(acc, 1, 4)              // pos10
        LOADA(A1, a1r, 12 + quad, 1)  COMPP(acc, 0, 5)              // pos11
                                      COMPP(acc, 1, 6)              // pos12

        // cell 1 -> h1(t) into A1[wb]
#pragma unroll
        for (int mt = 0; mt < 2; ++mt) {
#pragma unroll
            for (int r = 0; r < 4; ++r) {
                float ig = sigm(acc[mt][0][r]);
                float fg = sigm(acc[mt][1][r]);
                float gg = tanh_fast(acc[mt][2][r]);
                float og = sigm(acc[mt][3][r]);
                float cn = fg * c1[mt][r] + ig * gg;
                c1[mt][r] = cn;
                float h = og * tanh_fast(cn);
                int row = mt * 16 + quad * 4 + r;
                A1[a1w + ((u >> 3) * ROWP + row) * 8 + (u & 7)] = (_Float16)h;
            }
        }

        // ======== decode head (12 of 60 steps) ========
        if (t >= LOOKBACK) {
            BARRIER();                       // h1(t) visible
            int r = tid >> 4, sub = tid & 15;
            float p = 0.0f;
#pragma unroll
            for (int i = 0; i < HIDDEN / 16; ++i) {
                int uu = sub + i * 16;
                p += (float)A1[a1w + ((uu >> 3) * ROWP + r) * 8 + (uu & 7)] * wfcs[uu];
            }
#pragma unroll
            for (int off = 8; off; off >>= 1) p += __shfl_down(p, off, 16);
            if (sub == 0) {
                float pr = p + bfc;
                out[(size_t)(batch0 + r) * HORIZON + (t - LOOKBACK)] = pr;
                if (t + 1 < TTOT)            // BG feedback -> x(t+1) slot k=0 in A0[wb]
                    A0[a0w + r * 8] = (_Float16)pr;
            }
            BARRIER();                       // BG slot visible
        }
    }
#undef LOADB
#undef LOADA
#undef COMPQ
#undef COMPP
}

extern "C" void kernel_launch(void* const* d_in, const int* in_sizes, int n_in,
                              void* d_out, int out_size, void* d_ws, size_t ws_size,
                              hipStream_t stream) {
    const float* input = (const float*)d_in[0];
    const float* Wih0  = (const float*)d_in[1];
    const float* Whh0  = (const float*)d_in[2];
    const float* bi0   = (const float*)d_in[3];
    const float* bh0   = (const float*)d_in[4];
    const float* Wih1  = (const float*)d_in[5];
    const float* Whh1  = (const float*)d_in[6];
    const float* bi1   = (const float*)d_in[7];
    const float* bh1   = (const float*)d_in[8];
    const float* W_fc  = (const float*)d_in[9];
    const float* b_fc  = (const float*)d_in[10];

    _Float16* wfrag = (_Float16*)d_ws;
    float* bias = (float*)((char*)d_ws + (size_t)W_HALFS * sizeof(_Float16));

    int total = W_HALFS + 2 * GATES;
    setup_kernel<<<(total + 255) / 256, 256, 0, stream>>>(
        Wih0, Whh0, bi0, bh0, Wih1, Whh1, bi1, bh1, wfrag, bias);

    lstm_kernel<<<BATCH / TILE_B, NTHREADS, 0, stream>>>(
        input, wfrag, bias, W_fc, b_fc, (float*)d_out);
}

// Round 12
// 370.885 us; speedup vs baseline: 1.0217x; 1.0217x over previous
//
#include <hip/hip_runtime.h>

#define LOOKBACK 48
#define HORIZON  12
#define TTOT     60
#define INPUT_DIM 8
#define HIDDEN   128
#define GATES    512
#define BATCH    8192
#define TILE_B   32          /* batch rows per block (2 M-tiles of 16) */
#define NTHREADS 512         /* 8 waves; wave s owns hidden units s*16..s*16+15 */
#define NSLICES  8
#define L0_KS    5           /* layer0 K = 160 (8 x + 128 h0 + 24 zero-pad) */
#define L1_KS    8           /* layer1 K = 256 (128 h0 + 128 h1) */
#define NPOS     (L0_KS + L1_KS)
#define FRAGS_PER_KS 4       /* 4 gate-type N-tiles, single fp16 B */
#define FRAG_SHORTS 512      /* 1KB per fragment */
#define KSTRIDE  (FRAGS_PER_KS * FRAG_SHORTS)            /* 2048 halves per K-step */
#define SLICE_FRAGS (NPOS * FRAGS_PER_KS)                /* 52 */
#define W_HALFS  (NSLICES * SLICE_FRAGS * FRAG_SHORTS)   /* 212992 halves = 416KB */

/* A-plane LDS, parity double-buffered (1 barrier/encoder step):
   A0[par]: chunk0 = x, chunks 1..16 = h0 (chunk 1+(u>>3)), 17..19 zero pad.
   A1[par]: chunks 0..15 = h1.
   chunk = [ROWP rows][8 fp16], ROWP=33 (32 rows + 1 pad row). */
#define ROWP 33
#define A0_CHUNKS 20
#define A1_CHUNKS 16
#define A0_BUF (A0_CHUNKS * ROWP * 8)      /* 5280 */
#define A1_BUF (A1_CHUNKS * ROWP * 8)      /* 4224 */
#define A0_HALFS (2 * A0_BUF)
#define A1_HALFS (2 * A1_BUF)

typedef __attribute__((ext_vector_type(8))) _Float16 half8;
typedef __attribute__((ext_vector_type(4))) float f32x4;

__device__ __forceinline__ float frcp(float x) { return __builtin_amdgcn_rcpf(x); }
__device__ __forceinline__ float sigm(float x) {
    return frcp(1.0f + __expf(-x));
}
/* tanh(x) = 2*sigm(2x)-1 : fewer VALU ops, exact at extremes (rcp(inf)=0) */
__device__ __forceinline__ float tanh_fast(float x) {
    return __builtin_fmaf(2.0f, frcp(1.0f + __expf(-2.0f * x)), -1.0f);
}

/* Barrier WITHOUT vmcnt drain: LDS ordering only; global loads stay in flight. */
#define BARRIER() __asm__ volatile("s_waitcnt lgkmcnt(0)\ns_barrier" ::: "memory")

// ------------- setup: fp16 weights in MFMA-fragment order -------------
__global__ void setup_kernel(const float* __restrict__ Wih0, const float* __restrict__ Whh0,
                             const float* __restrict__ bi0,  const float* __restrict__ bh0,
                             const float* __restrict__ Wih1, const float* __restrict__ Whh1,
                             const float* __restrict__ bi1,  const float* __restrict__ bh1,
                             _Float16* __restrict__ wfrag, float* __restrict__ bias) {
    int idx = blockIdx.x * blockDim.x + threadIdx.x;
    if (idx < W_HALFS) {
        int e = idx & 511, frag = idx >> 9;
        int lane = e >> 3, j = e & 7;
        int t = frag & 3;
        int rest = frag >> 2;
        int lks = rest % NPOS, s = rest / NPOS;
        int l = (lks < L0_KS) ? 0 : 1;
        int ks = l ? (lks - L0_KS) : lks;
        int k = ks * 32 + ((lane >> 4) << 3) + j;
        int uu = s * 16 + (lane & 15);
        int row = t * HIDDEN + uu;
        float v = 0.0f;
        if (l == 0) {
            if (k < INPUT_DIM) v = Wih0[row * INPUT_DIM + k];
            else if (k < INPUT_DIM + HIDDEN) v = Whh0[row * HIDDEN + (k - INPUT_DIM)];
        } else {
            if (k < HIDDEN) v = Wih1[row * HIDDEN + k];
            else v = Whh1[row * HIDDEN + (k - HIDDEN)];
        }
        wfrag[idx] = (_Float16)v;
    } else if (idx < W_HALFS + 2 * GATES) {
        int g = idx - W_HALFS;
        bias[g] = (g < GATES) ? (bi0[g] + bh0[g]) : (bi1[g - GATES] + bh1[g - GATES]);
    }
}

// ------------- persistent 2-layer LSTM: unroll-2, cross-step pipelined -------------
__global__ __launch_bounds__(NTHREADS, 2)
void lstm_kernel(const float* __restrict__ input,   // [B,60,8]
                 const _Float16* __restrict__ wfrag,
                 const float* __restrict__ bias01,  // [1024]
                 const float* __restrict__ W_fc,    // [128]
                 const float* __restrict__ b_fc,
                 float* __restrict__ out) {         // [B,12]
    __shared__ _Float16 A0[A0_HALFS];
    __shared__ _Float16 A1[A1_HALFS];
    __shared__ float wfcs[HIDDEN];

    const int tid  = threadIdx.x;
    const int lane = tid & 63;
    const int s    = tid >> 6;
    const int col  = lane & 15;
    const int quad = lane >> 4;
    const int u    = s * 16 + col;
    const int batch0 = blockIdx.x * TILE_B;

    /* wave-uniform weight base -> SGPR addressing */
    uintptr_t wp64 = (uintptr_t)(wfrag + s * (SLICE_FRAGS * FRAG_SHORTS));
    wp64 = ((uintptr_t)__builtin_amdgcn_readfirstlane((unsigned)(wp64 >> 32)) << 32)
         | __builtin_amdgcn_readfirstlane((unsigned)wp64);
    const _Float16* wbase = (const _Float16*)wp64;

    for (int i = tid; i < A0_HALFS; i += NTHREADS) A0[i] = (_Float16)0.f;
    for (int i = tid; i < A1_HALFS; i += NTHREADS) A1[i] = (_Float16)0.f;
    if (tid < HIDDEN) wfcs[tid] = W_fc[tid];
    const float bfc = b_fc[0];

    float bv0[4], bv1[4];
#pragma unroll
    for (int tt = 0; tt < 4; ++tt) {
        bv0[tt] = bias01[tt * HIDDEN + u];
        bv1[tt] = bias01[GATES + tt * HIDDEN + u];
    }

    float c0[2][4] = {}, c1[2][4] = {};

    // x(0) prefetch + stage into parity-0 buffer
    {
        float x0 = 0.0f;
        if (tid < TILE_B * INPUT_DIM)
            x0 = input[(size_t)(batch0 + (tid >> 3)) * (TTOT * INPUT_DIM) + (tid & 7)];
        BARRIER();                           // zero-init visible
        if (tid < TILE_B * INPUT_DIM)
            A0[(tid >> 3) * 8 + (tid & 7)] = (_Float16)x0;
    }

    half8 bq[3][4];                          // B conveyor (depth 3, 4 gate frags)
    half8 ah[2][2];                          // A double buffer x 2 M-tiles

#define LOADB(p, sl) {                                                          \
    _Pragma("unroll") for (int tt = 0; tt < 4; ++tt)                            \
        bq[sl][tt] = *(const half8*)(wbase + (p) * KSTRIDE                      \
                                     + tt * FRAG_SHORTS + lane * 8); }
#define LOADA(H, off, chunk, buf) { int base_ = (off) + ((chunk) * ROWP + col) * 8; \
    ah[buf][0] = *(const half8*)(H + base_);                                    \
    ah[buf][1] = *(const half8*)(H + base_ + 16 * 8); }
#define COMPQ(ACC, ab, sl)                                                      \
    _Pragma("unroll") for (int tt = 0; tt < 4; ++tt)                            \
    _Pragma("unroll") for (int mt = 0; mt < 2; ++mt)                            \
        ACC[mt][tt] = __builtin_amdgcn_mfma_f32_16x16x32_f16(                   \
            ah[ab][mt], bq[sl][tt], ACC[mt][tt], 0, 0, 0);

    LOADB(0, 0) LOADB(1, 1) LOADB(2, 2)      // prime B conveyor
    BARRIER();                               // x(0) staged & visible
    /* prime A pipeline: GEMM0(0) pos0/pos1 */
    LOADA(A0, 0, quad, 0)
    LOADA(A0, 0, 4 + quad, 1)

/* One timestep with compile-time parity RB. ah[0]=pos0, ah[1]=pos1 already
   loaded (pre-loop prime, previous step's tail-hoist, or head-reload). */
#define STEP(TC, RB) {                                                          \
    const int a0r = (RB) * A0_BUF, a0w = ((RB) ^ 1) * A0_BUF;                   \
    const int a1r = (RB) * A1_BUF, a1w = ((RB) ^ 1) * A1_BUF;                   \
    float xv = 0.0f;                                                            \
    if (tid < TILE_B * INPUT_DIM && (TC) + 1 < TTOT)                            \
        xv = input[(size_t)(batch0 + (tid >> 3)) * (TTOT * INPUT_DIM)           \
                   + ((TC) + 1) * INPUT_DIM + (tid & 7)];                       \
    /* head-reload after a decode step's B6 (BG slot safety) */                 \
    if ((TC) > LOOKBACK) {                                                      \
        LOADA(A0, a0r, quad, 0)                                                 \
        LOADA(A0, a0r, 4 + quad, 1)                                             \
    }                                                                           \
    /* ---- P1: GEMM0 reads A0[rb], stream pos 0..4 ---- */                     \
    f32x4 acc[2][4];                                                            \
    _Pragma("unroll") for (int tt = 0; tt < 4; ++tt) {                          \
        f32x4 b = {bv0[tt], bv0[tt], bv0[tt], bv0[tt]};                         \
        acc[0][tt] = b; acc[1][tt] = b;                                         \
    }                                                                           \
    COMPQ(acc, 0, 0) LOADB(3, 0) LOADA(A0, a0r, 8 + quad, 0)                    \
    COMPQ(acc, 1, 1) LOADB(4, 1) LOADA(A0, a0r, 12 + quad, 1)                   \
    COMPQ(acc, 0, 2) LOADB(5, 2) LOADA(A0, a0r, 16 + quad, 0)                   \
    COMPQ(acc, 1, 0) LOADB(6, 0)                                                \
    COMPQ(acc, 0, 1) LOADB(7, 1)                                                \
    /* cell 0 -> h0(t) into A0[wb] chunks 1..16 */                              \
    _Pragma("unroll") for (int mt = 0; mt < 2; ++mt) {                          \
        _Pragma("unroll") for (int r = 0; r < 4; ++r) {                         \
            float ig = sigm(acc[mt][0][r]);                                     \
            float fg = sigm(acc[mt][1][r]);                                     \
            float gg = tanh_fast(acc[mt][2][r]);                                \
            float og = sigm(acc[mt][3][r]);                                     \
            float cn = fg * c0[mt][r] + ig * gg;                                \
            c0[mt][r] = cn;                                                     \
            float h = og * tanh_fast(cn);                                       \
            int row = mt * 16 + quad * 4 + r;                                   \
            A0[a0w + ((1 + (u >> 3)) * ROWP + row) * 8 + (u & 7)] = (_Float16)h;\
        }                                                                       \
    }                                                                           \
    /* stage x(t+1) into A0[wb] chunk 0 (BG slot from fc in decode) */          \
    if (tid < TILE_B * INPUT_DIM && (TC) + 1 < TTOT) {                          \
        int r = tid >> 3, k = tid & 7;                                          \
        if (!((TC) + 1 > LOOKBACK && k == 0))                                   \
            A0[a0w + r * 8 + k] = (_Float16)xv;                                 \
    }                                                                           \
    BARRIER();                               /* the ONLY encoder barrier */     \
    /* ---- P2: GEMM1 reads h0 from A0[wb], h1 from A1[rb]; pos 5..12 ---- */   \
    _Pragma("unroll") for (int tt = 0; tt < 4; ++tt) {                          \
        f32x4 b = {bv1[tt], bv1[tt], bv1[tt], bv1[tt]};                         \
        acc[0][tt] = b; acc[1][tt] = b;                                         \
    }                                                                           \
    LOADA(A0, a0w, 1 + quad, 0)                                                 \
    LOADA(A0, a0w, 5 + quad, 1)   COMPQ(acc, 0, 2) LOADB(8, 2)                  \
    LOADA(A0, a0w, 9 + quad, 0)   COMPQ(acc, 1, 0) LOADB(9, 0)                  \
    LOADA(A0, a0w, 13 + quad, 1)  COMPQ(acc, 0, 1) LOADB(10, 1)                 \
    LOADA(A1, a1r, quad, 0)       COMPQ(acc, 1, 2) LOADB(11, 2)                 \
    LOADA(A1, a1r, 4 + quad, 1)   COMPQ(acc, 0, 0) LOADB(12, 0)                 \
    LOADA(A1, a1r, 8 + quad, 0)   COMPQ(acc, 1, 1) LOADB(1, 1)                  \
    LOADA(A1, a1r, 12 + quad, 1)  COMPQ(acc, 0, 2) LOADB(2, 2)                  \
                                  COMPQ(acc, 1, 0) LOADB(0, 0)                  \
    /* cell 1 -> h1(t) into A1[wb] */                                           \
    _Pragma("unroll") for (int mt = 0; mt < 2; ++mt) {                          \
        _Pragma("unroll") for (int r = 0; r < 4; ++r) {                         \
            float ig = sigm(acc[mt][0][r]);                                     \
            float fg = sigm(acc[mt][1][r]);                                     \
            float gg = tanh_fast(acc[mt][2][r]);                                \
            float og = sigm(acc[mt][3][r]);                                     \
            float cn = fg * c1[mt][r] + ig * gg;                                \
            c1[mt][r] = cn;                                                     \
            float h = og * tanh_fast(cn);                                       \
            int row = mt * 16 + quad * 4 + r;                                   \
            A1[a1w + ((u >> 3) * ROWP + row) * 8 + (u & 7)] = (_Float16)h;      \
        }                                                                       \
    }                                                                           \
    /* tail-hoist next step's GEMM0 pos0/pos1 (encoder only: no B6 hazard) */   \
    if ((TC) < LOOKBACK) {                                                      \
        LOADA(A0, a0w, quad, 0)                                                 \
        LOADA(A0, a0w, 4 + quad, 1)                                             \
    }                                                                           \
    /* ---- decode head (t >= LOOKBACK) ---- */                                 \
    if ((TC) >= LOOKBACK) {                                                     \
        BARRIER();                           /* B5: h1(t) visible */            \
        int r = tid >> 4, sub = tid & 15;                                       \
        float p = 0.0f;                                                         \
        _Pragma("unroll") for (int i = 0; i < HIDDEN / 16; ++i) {               \
            int uu = sub + i * 16;                                              \
            p += (float)A1[a1w + ((uu >> 3) * ROWP + r) * 8 + (uu & 7)]         \
                 * wfcs[uu];                                                    \
        }                                                                       \
        _Pragma("unroll") for (int off = 8; off; off >>= 1)                     \
            p += __shfl_down(p, off, 16);                                       \
        if (sub == 0) {                                                         \
            float pr = p + bfc;                                                 \
            out[(size_t)(batch0 + r) * HORIZON + ((TC) - LOOKBACK)] = pr;       \
            if ((TC) + 1 < TTOT)                                                \
                A0[a0w + r * 8] = (_Float16)pr;                                 \
        }                                                                       \
        BARRIER();                           /* B6: BG slot visible */          \
    }                                                                           \
}

#pragma unroll 1
    for (int t = 0; t < TTOT; t += 2) {
        STEP(t, 0)
        STEP(t + 1, 1)
    }
#undef STEP
#undef LOADB
#undef LOADA
#undef COMPQ
}

extern "C" void kernel_launch(void* const* d_in, const int* in_sizes, int n_in,
                              void* d_out, int out_size, void* d_ws, size_t ws_size,
                              hipStream_t stream) {
    const float* input = (const float*)d_in[0];
    const float* Wih0  = (const float*)d_in[1];
    const float* Whh0  = (const float*)d_in[2];
    const float* bi0   = (const float*)d_in[3];
    const float* bh0   = (const float*)d_in[4];
    const float* Wih1  = (const float*)d_in[5];
    const float* Whh1  = (const float*)d_in[6];
    const float* bi1   = (const float*)d_in[7];
    const float* bh1   = (const float*)d_in[8];
    const float* W_fc  = (const float*)d_in[9];
    const float* b_fc  = (const float*)d_in[10];

    _Float16* wfrag = (_Float16*)d_ws;
    float* bias = (float*)((char*)d_ws + (size_t)W_HALFS * sizeof(_Float16));

    int total = W_HALFS + 2 * GATES;
    setup_kernel<<<(total + 255) / 256, 256, 0, stream>>>(
        Wih0, Whh0, bi0, bh0, Wih1, Whh1, bi1, bh1, wfrag, bias);

    lstm_kernel<<<BATCH / TILE_B, NTHREADS, 0, stream>>>(
        input, wfrag, bias, W_fc, b_fc, (float*)d_out);
}